// Round 1
// baseline (469.434 us; speedup 1.0000x reference)
//
#include <hip/hip_runtime.h>
#include <math.h>

#define NV   6890
#define NJ   24
#define NB   10
#define NPF  207
#define NCJ  19
#define BATCHN 1024

// output float offsets
#define OUT_JOINTS_OFF (BATCHN*NV*3)               // 21166080
#define OUT_RS_OFF     (OUT_JOINTS_OFF + BATCHN*NCJ*3)  // 21224448

// workspace float offsets
#define WS_JS    0        // [24][33]
#define WS_PF    4096     // [1024][207]
#define WS_AADJ  217088   // [1024][24][12]

// ---------------- Kernel A: fold J_regressor into shapedirs/v_template ----
// js[j][33]: [0..29] = sum_v Jreg[j][v]*shapedirs[k][v*3+d] (k*3+d), [30..32] = Jreg@v_template
__global__ void smpl_kA(const float* __restrict__ jreg, const float* __restrict__ sdirs,
                        const float* __restrict__ vtmpl, float* __restrict__ js) {
    int j = blockIdx.x;
    int tid = threadIdx.x;  // 256
    float acc[33];
#pragma unroll
    for (int e = 0; e < 33; e++) acc[e] = 0.f;
    for (int v = tid; v < NV; v += 256) {
        float w = jreg[j * NV + v];
#pragma unroll
        for (int k = 0; k < NB; k++) {
#pragma unroll
            for (int d = 0; d < 3; d++)
                acc[k * 3 + d] += w * sdirs[(size_t)k * (NV * 3) + v * 3 + d];
        }
#pragma unroll
        for (int d = 0; d < 3; d++) acc[30 + d] += w * vtmpl[v * 3 + d];
    }
#pragma unroll
    for (int e = 0; e < 33; e++) {
#pragma unroll
        for (int off = 32; off >= 1; off >>= 1) acc[e] += __shfl_xor(acc[e], off, 64);
    }
    __shared__ float red[4][33];
    int lane = tid & 63, wv = tid >> 6;
    if (lane == 0) {
#pragma unroll
        for (int e = 0; e < 33; e++) red[wv][e] = acc[e];
    }
    __syncthreads();
    if (tid < 33) js[j * 33 + tid] = red[0][tid] + red[1][tid] + red[2][tid] + red[3][tid];
}

// ---------------- Kernel B: Rodrigues + chain -----------------------------
__global__ void smpl_kB(const float* __restrict__ theta, const float* __restrict__ beta_,
                        const float* __restrict__ js, float* __restrict__ outRs,
                        float* __restrict__ pf, float* __restrict__ aadj) {
    int b = blockIdx.x;
    int t = threadIdx.x;  // 64
    __shared__ float Rl[NJ][9];
    __shared__ float Jl[NJ][3];
    __shared__ float Rw[NJ][12];

    if (t < NJ) {
        int j = t;
        float tx = theta[b * 72 + j * 3 + 0];
        float ty = theta[b * 72 + j * 3 + 1];
        float tz = theta[b * 72 + j * 3 + 2];
        float ax = tx + 1e-8f, ay = ty + 1e-8f, az = tz + 1e-8f;
        float ang = sqrtf(ax * ax + ay * ay + az * az);
        float inv = 1.0f / ang;
        float rx = tx * inv, ry = ty * inv, rz = tz * inv;
        float s = sinf(ang), c = cosf(ang), t1 = 1.0f - c;
        float R[9];
        R[0] = 1.0f - t1 * (ry * ry + rz * rz);
        R[1] = -s * rz + t1 * rx * ry;
        R[2] =  s * ry + t1 * rx * rz;
        R[3] =  s * rz + t1 * rx * ry;
        R[4] = 1.0f - t1 * (rx * rx + rz * rz);
        R[5] = -s * rx + t1 * ry * rz;
        R[6] = -s * ry + t1 * rx * rz;
        R[7] =  s * rx + t1 * ry * rz;
        R[8] = 1.0f - t1 * (rx * rx + ry * ry);
#pragma unroll
        for (int e = 0; e < 9; e++) {
            Rl[j][e] = R[e];
            outRs[(size_t)b * 216 + j * 9 + e] = R[e];
        }
        if (j >= 1) {
#pragma unroll
            for (int e = 0; e < 9; e++)
                pf[(size_t)b * NPF + (j - 1) * 9 + e] = R[e] - ((e == 0 || e == 4 || e == 8) ? 1.0f : 0.0f);
        }
        // J from folded regressor
#pragma unroll
        for (int d = 0; d < 3; d++) {
            float accJ = js[j * 33 + 30 + d];
#pragma unroll
            for (int k = 0; k < NB; k++) accJ += beta_[b * NB + k] * js[j * 33 + k * 3 + d];
            Jl[j][d] = accJ;
        }
    }
    __syncthreads();
    if (t == 0) {
        // joint 0: root_rot = R0 @ diag(1,-1,-1) -> negate cols 1,2
#pragma unroll
        for (int r = 0; r < 3; r++) {
            Rw[0][r * 4 + 0] =  Rl[0][r * 3 + 0];
            Rw[0][r * 4 + 1] = -Rl[0][r * 3 + 1];
            Rw[0][r * 4 + 2] = -Rl[0][r * 3 + 2];
            Rw[0][r * 4 + 3] =  Jl[0][r];
        }
        const int par[NJ] = {0,0,0,0,1,2,3,4,5,6,7,8,9,9,9,12,13,14,16,17,18,19,20,21};
#pragma unroll
        for (int i = 1; i < NJ; i++) {
            int p = par[i];
            float tr0 = Jl[i][0] - Jl[p][0];
            float tr1 = Jl[i][1] - Jl[p][1];
            float tr2 = Jl[i][2] - Jl[p][2];
#pragma unroll
            for (int r = 0; r < 3; r++) {
                float p0 = Rw[p][r * 4 + 0], p1 = Rw[p][r * 4 + 1], p2 = Rw[p][r * 4 + 2];
#pragma unroll
                for (int cc = 0; cc < 3; cc++)
                    Rw[i][r * 4 + cc] = p0 * Rl[i][0 + cc] + p1 * Rl[i][3 + cc] + p2 * Rl[i][6 + cc];
                Rw[i][r * 4 + 3] = p0 * tr0 + p1 * tr1 + p2 * tr2 + Rw[p][r * 4 + 3];
            }
        }
    }
    __syncthreads();
    for (int e = t; e < NJ * 12; e += 64) {
        int j = e / 12, rc = e % 12, r = rc >> 2, cc = rc & 3;
        float v;
        if (cc < 3) v = Rw[j][rc];
        else v = Rw[j][r * 4 + 3] - (Rw[j][r * 4 + 0] * Jl[j][0] + Rw[j][r * 4 + 1] * Jl[j][1] +
                                     Rw[j][r * 4 + 2] * Jl[j][2]);
        aadj[(size_t)b * 288 + e] = v;
    }
}

// ---------------- Kernel C: fused pose-GEMM + skinning --------------------
#define VT 32
#define BT 64
#define KC 32
#define KTOT 224  // 207 pf + 10 beta + 1 template + 6 zero

__global__ __launch_bounds__(256) void smpl_kC(
    const float* __restrict__ pdirs, const float* __restrict__ sdirs,
    const float* __restrict__ vtmpl, const float* __restrict__ beta_,
    const float* __restrict__ pf, const float* __restrict__ aadj,
    const float* __restrict__ wts, float* __restrict__ outv) {
    __shared__ float efs[BT][36];        // extended feature chunk
    __shared__ float pds[KC][100];       // extended dirs chunk (96 used, pad for banks)
    __shared__ float4 vph[BT][VT + 1];   // v_posed homogeneous
    __shared__ float wls[NJ][36];        // weights transposed (32 used)

    int tid = threadIdx.x;
    int vtile = blockIdx.x * VT;
    int btile = blockIdx.y * BT;

    for (int e = tid; e < NJ * VT; e += 256) {
        int j = e % NJ, vl = e / NJ;
        int v = vtile + vl;
        wls[j][vl] = (v < NV) ? wts[(size_t)v * NJ + j] : 0.f;
    }

    int tb = tid & 15, tv = tid >> 4;
    int tv3 = tv * 3;
    float acc[4][2][3] = {};

    for (int kc = 0; kc < KTOT; kc += KC) {
        __syncthreads();
        {   // stage extended features [64 b][32 k]
            int lb = tid & 63;
            int ko = (tid >> 6) * 8;
            int b = btile + lb;
#pragma unroll
            for (int u = 0; u < 8; u++) {
                int k = kc + ko + u;
                float val;
                if (k < NPF) val = pf[(size_t)b * NPF + k];
                else if (k < NPF + NB) val = beta_[b * NB + (k - NPF)];
                else if (k == NPF + NB) val = 1.0f;
                else val = 0.f;
                efs[lb][ko + u] = val;
            }
        }
        {   // stage extended dirs [32 k][96 cols]
            int r = tid & 31;
            int chunk = tid >> 5;  // 0..7
            int k = kc + r;
            int cbase = vtile * 3 + chunk * 12;
#pragma unroll
            for (int u = 0; u < 12; u++) {
                int col = cbase + u;
                float val = 0.f;
                if (col < NV * 3) {
                    if (k < NPF) val = pdirs[(size_t)k * (NV * 3) + col];
                    else if (k < NPF + NB) val = sdirs[(size_t)(k - NPF) * (NV * 3) + col];
                    else if (k == NPF + NB) val = vtmpl[col];
                }
                pds[r][chunk * 12 + u] = val;
            }
        }
        __syncthreads();
        for (int kk = 0; kk < KC; kk += 4) {
            float fa[4][4];
            *(float4*)&fa[0][0] = *(const float4*)&efs[tb + 0][kk];
            *(float4*)&fa[1][0] = *(const float4*)&efs[tb + 16][kk];
            *(float4*)&fa[2][0] = *(const float4*)&efs[tb + 32][kk];
            *(float4*)&fa[3][0] = *(const float4*)&efs[tb + 48][kk];
#pragma unroll
            for (int u = 0; u < 4; u++) {
                int k = kk + u;
                float p0 = pds[k][tv3 + 0], p1 = pds[k][tv3 + 1], p2 = pds[k][tv3 + 2];
                float q0 = pds[k][tv3 + 48], q1 = pds[k][tv3 + 49], q2 = pds[k][tv3 + 50];
#pragma unroll
                for (int i = 0; i < 4; i++) {
                    float e = fa[i][u];
                    acc[i][0][0] += e * p0; acc[i][0][1] += e * p1; acc[i][0][2] += e * p2;
                    acc[i][1][0] += e * q0; acc[i][1][1] += e * q1; acc[i][1][2] += e * q2;
                }
            }
        }
    }
    // publish v_posed (homogeneous) to LDS
#pragma unroll
    for (int i = 0; i < 4; i++)
#pragma unroll
        for (int j2 = 0; j2 < 2; j2++)
            vph[tb + 16 * i][tv + 16 * j2] =
                make_float4(acc[i][j2][0], acc[i][j2][1], acc[i][j2][2], 1.0f);
    __syncthreads();

    // phase 2: skinning. thread -> 1 batch x 8 verts
    int pb = tid >> 2;
    int pv = (tid & 3) * 8;
    int b = btile + pb;
    const float* ab = aadj + (size_t)b * 288;
    float T[8][12] = {};
#pragma unroll 4
    for (int j = 0; j < NJ; j++) {
        float4 a0 = *(const float4*)&ab[j * 12 + 0];
        float4 a1 = *(const float4*)&ab[j * 12 + 4];
        float4 a2 = *(const float4*)&ab[j * 12 + 8];
        float wv[8];
        *(float4*)&wv[0] = *(const float4*)&wls[j][pv];
        *(float4*)&wv[4] = *(const float4*)&wls[j][pv + 4];
#pragma unroll
        for (int vv = 0; vv < 8; vv++) {
            float w = wv[vv];
            T[vv][0] += w * a0.x; T[vv][1] += w * a0.y; T[vv][2]  += w * a0.z; T[vv][3]  += w * a0.w;
            T[vv][4] += w * a1.x; T[vv][5] += w * a1.y; T[vv][6]  += w * a1.z; T[vv][7]  += w * a1.w;
            T[vv][8] += w * a2.x; T[vv][9] += w * a2.y; T[vv][10] += w * a2.z; T[vv][11] += w * a2.w;
        }
    }
#pragma unroll
    for (int vv = 0; vv < 8; vv++) {
        int v = vtile + pv + vv;
        if (v < NV) {
            float4 x = vph[pb][pv + vv];
            float o0 = T[vv][0] * x.x + T[vv][1] * x.y + T[vv][2]  * x.z + T[vv][3];
            float o1 = T[vv][4] * x.x + T[vv][5] * x.y + T[vv][6]  * x.z + T[vv][7];
            float o2 = T[vv][8] * x.x + T[vv][9] * x.y + T[vv][10] * x.z + T[vv][11];
            size_t o = ((size_t)b * NV + v) * 3;
            outv[o + 0] = o0; outv[o + 1] = o1; outv[o + 2] = o2;
        }
    }
}

// ---------------- Kernel D: COCO joint regression -------------------------
__global__ void smpl_kD(const float* __restrict__ verts, const float* __restrict__ jr,
                        float* __restrict__ outj) {
    int b = blockIdx.x;
    int tid = threadIdx.x;  // 256
    float acc[NCJ][3];
#pragma unroll
    for (int j = 0; j < NCJ; j++)
#pragma unroll
        for (int d = 0; d < 3; d++) acc[j][d] = 0.f;
    const float* vb = verts + (size_t)b * NV * 3;
    for (int v = tid; v < NV; v += 256) {
        float x = vb[v * 3 + 0], y = vb[v * 3 + 1], z = vb[v * 3 + 2];
#pragma unroll
        for (int j = 0; j < NCJ; j++) {
            float w = jr[(size_t)j * NV + v];
            acc[j][0] += w * x; acc[j][1] += w * y; acc[j][2] += w * z;
        }
    }
#pragma unroll
    for (int j = 0; j < NCJ; j++)
#pragma unroll
        for (int d = 0; d < 3; d++)
#pragma unroll
            for (int off = 32; off >= 1; off >>= 1)
                acc[j][d] += __shfl_xor(acc[j][d], off, 64);
    __shared__ float red[4][57];
    int lane = tid & 63, wv = tid >> 6;
    if (lane == 0) {
#pragma unroll
        for (int e = 0; e < 57; e++) red[wv][e] = acc[e / 3][e % 3];
    }
    __syncthreads();
    if (tid < 57)
        outj[(size_t)b * 57 + tid] = red[0][tid] + red[1][tid] + red[2][tid] + red[3][tid];
}

extern "C" void kernel_launch(void* const* d_in, const int* in_sizes, int n_in,
                              void* d_out, int out_size, void* d_ws, size_t ws_size,
                              hipStream_t stream) {
    (void)in_sizes; (void)n_in; (void)out_size; (void)ws_size;
    const float* beta      = (const float*)d_in[0];
    const float* theta     = (const float*)d_in[1];
    const float* v_template= (const float*)d_in[2];
    const float* shapedirs = (const float*)d_in[3];
    const float* jreg      = (const float*)d_in[4];
    const float* posedirs  = (const float*)d_in[5];
    const float* jointreg  = (const float*)d_in[6];
    const float* weights   = (const float*)d_in[7];
    float* out = (float*)d_out;
    float* ws  = (float*)d_ws;

    smpl_kA<<<NJ, 256, 0, stream>>>(jreg, shapedirs, v_template, ws + WS_JS);
    smpl_kB<<<BATCHN, 64, 0, stream>>>(theta, beta, ws + WS_JS, out + OUT_RS_OFF,
                                       ws + WS_PF, ws + WS_AADJ);
    dim3 gC((NV + VT - 1) / VT, BATCHN / BT);
    smpl_kC<<<gC, 256, 0, stream>>>(posedirs, shapedirs, v_template, beta,
                                    ws + WS_PF, ws + WS_AADJ, weights, out);
    smpl_kD<<<BATCHN, 256, 0, stream>>>(out, jointreg, out + OUT_JOINTS_OFF);
}